// Round 1
// baseline (2240.884 us; speedup 1.0000x reference)
//
#include <hip/hip_runtime.h>
#include <hip/hip_bf16.h>

// Problem constants
#define S_LEN   1024
#define BATCH   4
#define DMODEL  2048
#define NHEADS  16
#define NKVH    8
#define HEADD   128
#define NTOK    4096      // BATCH*S_LEN
#define QKV_CH  4096      // 2048 q + 1024 k + 1024 v

typedef __bf16 bf16x8 __attribute__((ext_vector_type(8)));
typedef float  f32x4  __attribute__((ext_vector_type(4)));

__device__ __forceinline__ float bf2f(unsigned short u) {
    return __uint_as_float(((unsigned)u) << 16);
}

// ---------------- fp32 -> bf16 cast, 4 elems/thread ----------------
__global__ __launch_bounds__(256) void cast_kernel(const float* __restrict__ in,
                                                   __hip_bfloat16* __restrict__ out, int n4) {
    int i = blockIdx.x * 256 + threadIdx.x;
    if (i >= n4) return;
    float4 v = ((const float4*)in)[i];
    union { ushort4 u; __hip_bfloat16 h[4]; } r;
    r.h[0] = __float2bfloat16(v.x);
    r.h[1] = __float2bfloat16(v.y);
    r.h[2] = __float2bfloat16(v.z);
    r.h[3] = __float2bfloat16(v.w);
    ((ushort4*)out)[i] = r.u;
}

// ---------------- gate: logits -> softmax -> top2 -> dense expert weights ----------------
__global__ __launch_bounds__(256) void gate_kernel(const float* __restrict__ X,
                                                   const float* __restrict__ GW,
                                                   float* __restrict__ EW) {
    __shared__ float red[4][257];
    const int t = blockIdx.x, tid = threadIdx.x;
    const float* x = X + (size_t)t * DMODEL;
    float p0 = 0.f, p1 = 0.f, p2 = 0.f, p3 = 0.f;
    for (int d = tid; d < DMODEL; d += 256) {
        float xv = x[d];
        p0 += xv * GW[d];
        p1 += xv * GW[DMODEL + d];
        p2 += xv * GW[2 * DMODEL + d];
        p3 += xv * GW[3 * DMODEL + d];
    }
    red[0][tid] = p0; red[1][tid] = p1; red[2][tid] = p2; red[3][tid] = p3;
    __syncthreads();
    for (int s = 128; s > 0; s >>= 1) {
        if (tid < s) {
            red[0][tid] += red[0][tid + s];
            red[1][tid] += red[1][tid + s];
            red[2][tid] += red[2][tid + s];
            red[3][tid] += red[3][tid + s];
        }
        __syncthreads();
    }
    if (tid == 0) {
        float l[4] = { red[0][0], red[1][0], red[2][0], red[3][0] };
        float mx = fmaxf(fmaxf(l[0], l[1]), fmaxf(l[2], l[3]));
        float pe[4], sum = 0.f;
        for (int e = 0; e < 4; e++) { pe[e] = __expf(l[e] - mx); sum += pe[e]; }
        float inv = 1.0f / sum;
        for (int e = 0; e < 4; e++) pe[e] *= inv;
        int i1 = 0;
        for (int e = 1; e < 4; e++) if (pe[e] > pe[i1]) i1 = e;
        int i2 = -1;
        for (int e = 0; e < 4; e++) if (e != i1 && (i2 < 0 || pe[e] > pe[i2])) i2 = e;
        float o[4] = {0.f, 0.f, 0.f, 0.f};
        o[i1] = pe[i1]; o[i2] = pe[i2];
        float* ew = EW + (size_t)t * 4;
        ew[0] = o[0]; ew[1] = o[1]; ew[2] = o[2]; ew[3] = o[3];
    }
}

// ---------------- bf16 MFMA GEMM: C[M][N] = A[M][K] * B[N][K]^T ----------------
// 128x128 tile, 4 waves each 64x64 (4x4 of 16x16x32 mfma), BK=32, fp32 out.
__global__ __launch_bounds__(256) void gemm_bt(const ushort* __restrict__ A,
                                               const ushort* __restrict__ B,
                                               float* __restrict__ C,
                                               int M, int N, int K) {
    __shared__ ushort As[128 * 32];
    __shared__ ushort Bs[128 * 32];
    const int tid  = threadIdx.x;
    const int wave = tid >> 6, lane = tid & 63;
    const int l16  = lane & 15, quad = lane >> 4;
    const int m0 = blockIdx.y * 128, n0 = blockIdx.x * 128;
    const int wm = (wave >> 1) * 64, wn = (wave & 1) * 64;

    f32x4 acc[4][4];
#pragma unroll
    for (int i = 0; i < 4; i++)
#pragma unroll
        for (int j = 0; j < 4; j++) acc[i][j] = (f32x4){0.f, 0.f, 0.f, 0.f};

    for (int k0 = 0; k0 < K; k0 += 32) {
        __syncthreads();
#pragma unroll
        for (int c0 = 0; c0 < 512; c0 += 256) {
            int c = c0 + tid;
            int row = c >> 2, kg = c & 3;
            ((uint4*)As)[c] = *(const uint4*)(A + (size_t)(m0 + row) * K + k0 + kg * 8);
            ((uint4*)Bs)[c] = *(const uint4*)(B + (size_t)(n0 + row) * K + k0 + kg * 8);
        }
        __syncthreads();
        bf16x8 af[4], bfr[4];
#pragma unroll
        for (int i = 0; i < 4; i++) {
            af[i]  = *(const bf16x8*)(As + (wm + i * 16 + l16) * 32 + quad * 8);
            bfr[i] = *(const bf16x8*)(Bs + (wn + i * 16 + l16) * 32 + quad * 8);
        }
#pragma unroll
        for (int i = 0; i < 4; i++)
#pragma unroll
            for (int j = 0; j < 4; j++)
                acc[i][j] = __builtin_amdgcn_mfma_f32_16x16x32_bf16(af[i], bfr[j], acc[i][j], 0, 0, 0);
    }
#pragma unroll
    for (int i = 0; i < 4; i++)
#pragma unroll
        for (int j = 0; j < 4; j++)
#pragma unroll
            for (int r = 0; r < 4; r++) {
                int m = m0 + wm + i * 16 + quad * 4 + r;
                int n = n0 + wn + j * 16 + l16;
                C[(size_t)m * N + n] = acc[i][j][r];
            }
}

// ---------------- RMSNorm + RoPE, in place on fp32 QKV ----------------
// rows: 65536 q rows (token,head) then 32768 k rows (token,kvhead). v untouched.
__global__ __launch_bounds__(256) void normrope_kernel(float* __restrict__ QKV,
                                                       const float* __restrict__ cosb,
                                                       const float* __restrict__ sinb,
                                                       const float* __restrict__ qw,
                                                       const float* __restrict__ kw) {
    const int wave = threadIdx.x >> 6, lane = threadIdx.x & 63;
    const int r = blockIdx.x * 4 + wave;
    float* p; const float* w; int t;
    if (r < NTOK * NHEADS) {
        t = r >> 4;
        int h = r & 15;
        p = QKV + (size_t)t * QKV_CH + h * HEADD;
        w = qw;
    } else {
        int r2 = r - NTOK * NHEADS;
        t = r2 >> 3;
        int kv = r2 & 7;
        p = QKV + (size_t)t * QKV_CH + 2048 + kv * HEADD;
        w = kw;
    }
    float xl = p[lane], xh = p[lane + 64];
    float ss = xl * xl + xh * xh;
#pragma unroll
    for (int mask = 1; mask < 64; mask <<= 1) ss += __shfl_xor(ss, mask);
    float rstd = rsqrtf(ss * (1.0f / 128.0f) + 1e-6f);
    float nl = xl * rstd * w[lane];
    float nh = xh * rstd * w[lane + 64];
    const float* cp = cosb + (size_t)t * HEADD;
    const float* sp = sinb + (size_t)t * HEADD;
    float ol = nl * cp[lane]      - nh * sp[lane];
    float oh = nh * cp[lane + 64] + nl * sp[lane + 64];
    p[lane] = ol;
    p[lane + 64] = oh;
}

// ---------------- causal attention, online softmax, fp32 ----------------
// block = 4 waves = 4 consecutive q rows of one (b,h); K/V staged in 32-key LDS tiles.
__global__ __launch_bounds__(256) void attn_kernel(const float* __restrict__ QKV,
                                                   __hip_bfloat16* __restrict__ O) {
    __shared__ float Ks[32 * 128];
    __shared__ float Vs[32 * 128];
    const int tid = threadIdx.x;
    const int wave = tid >> 6, lane = tid & 63;
    const int qblk = blockIdx.x & 255;   // S/4
    const int bh = blockIdx.x >> 8;
    const int b = bh >> 4, h = bh & 15;
    const int kv = h >> 1;
    const int q0 = qblk * 4;
    const int q_r = q0 + wave;
    const int tq = b * S_LEN + q_r;
    const int l16 = lane & 15, g = lane >> 4;
    const float scaling = 0.08838834764831845f;  // 128^-0.5

    const float* qrow = QKV + (size_t)tq * QKV_CH + h * HEADD;
    float4 qa = *(const float4*)(qrow + l16 * 8);
    float4 qb = *(const float4*)(qrow + l16 * 8 + 4);
    qa.x *= scaling; qa.y *= scaling; qa.z *= scaling; qa.w *= scaling;
    qb.x *= scaling; qb.y *= scaling; qb.z *= scaling; qb.w *= scaling;

    float m = -1e30f, lsum = 0.f, o0 = 0.f, o1 = 0.f;
    const float* kbase = QKV + ((size_t)b * S_LEN) * QKV_CH + 2048 + kv * HEADD;
    const float* vbase = kbase + 1024;
    const int ntiles = ((q0 + 3) >> 5) + 1;

    for (int kb = 0; kb < ntiles; kb++) {
        __syncthreads();
        for (int c = tid; c < 1024; c += 256) {
            int key = c >> 5, off = c & 31;
            ((float4*)Ks)[(key << 5) + off] = *(const float4*)(kbase + (size_t)(kb * 32 + key) * QKV_CH + off * 4);
            ((float4*)Vs)[(key << 5) + off] = *(const float4*)(vbase + (size_t)(kb * 32 + key) * QKV_CH + off * 4);
        }
        __syncthreads();
        for (int jj = 0; jj < 32; jj += 4) {
            int j = (kb << 5) + jj;
            if (j > q_r) break;                         // wave-uniform
            int jk = jj + g;                            // this group's key
            const float* krow = Ks + (jk << 7) + (l16 << 3);
            float4 k0 = *(const float4*)krow;
            float4 k1 = *(const float4*)(krow + 4);
            float part = qa.x * k0.x + qa.y * k0.y + qa.z * k0.z + qa.w * k0.w
                       + qb.x * k1.x + qb.y * k1.y + qb.z * k1.z + qb.w * k1.w;
            part += __shfl_xor(part, 1);
            part += __shfl_xor(part, 2);
            part += __shfl_xor(part, 4);
            part += __shfl_xor(part, 8);
#pragma unroll
            for (int g2 = 0; g2 < 4; g2++) {
                if (j + g2 > q_r) break;                // wave-uniform
                float s = __shfl(part, g2 * 16);
                float mn = fmaxf(m, s);
                float sc = __expf(m - mn);
                float pv = __expf(s - mn);
                lsum = lsum * sc + pv;
                const float2 vv = *(const float2*)(Vs + ((jj + g2) << 7) + (lane << 1));
                o0 = o0 * sc + pv * vv.x;
                o1 = o1 * sc + pv * vv.y;
                m = mn;
            }
        }
    }
    float inv = 1.0f / lsum;
    __hip_bfloat16* op = O + (size_t)tq * (NHEADS * HEADD) + h * HEADD + (lane << 1);
    op[0] = __float2bfloat16(o0 * inv);
    op[1] = __float2bfloat16(o1 * inv);
}

// ---------------- LoRA MoE correction: out += sum_e w_e*2 * B_e (A_e x) ----------------
__global__ __launch_bounds__(256) void lora_kernel(const __hip_bfloat16* __restrict__ X,
                                                   const float* __restrict__ lA,
                                                   const float* __restrict__ lB,
                                                   const float* __restrict__ EW,
                                                   float* __restrict__ out) {
    __shared__ float xs[DMODEL];
    __shared__ float hred[16][17];
    __shared__ float hs[16];
    const int t = blockIdx.x, tid = threadIdx.x;

    // stage x (bf16 -> fp32) into LDS
    const ushort4* src = (const ushort4*)(X + (size_t)t * DMODEL);
    for (int c = tid; c < 512; c += 256) {
        ushort4 u = src[c];
        xs[c * 4 + 0] = bf2f(u.x);
        xs[c * 4 + 1] = bf2f(u.y);
        xs[c * 4 + 2] = bf2f(u.z);
        xs[c * 4 + 3] = bf2f(u.w);
    }
    float ew0 = EW[(size_t)t * 4 + 0], ew1 = EW[(size_t)t * 4 + 1];
    float ew2 = EW[(size_t)t * 4 + 2], ew3 = EW[(size_t)t * 4 + 3];
    float ew[4] = { ew0, ew1, ew2, ew3 };
    __syncthreads();

    float acc[8];
#pragma unroll
    for (int i = 0; i < 8; i++) acc[i] = 0.f;

    const int r = tid >> 4, g = tid & 15;
    for (int e = 0; e < 4; e++) {
        float w = ew[e];
        if (w == 0.f) continue;                     // block-uniform
        // h[r] = sum_d x[d] * A[e][r][d]
        const float* Ar = lA + ((size_t)e * 16 + r) * DMODEL;
        float p = 0.f;
        for (int i = 0; i < 128; i++) {
            int d = g + (i << 4);
            p += xs[d] * Ar[d];
        }
        __syncthreads();                            // protect hred/hs WAR from prev expert
        hred[r][g] = p;
        __syncthreads();
        if (tid < 16) {
            float s = 0.f;
#pragma unroll
            for (int g2 = 0; g2 < 16; g2++) s += hred[tid][g2];
            hs[tid] = s;
        }
        __syncthreads();
        float wl = w * 2.0f;                        // LORA_SCALE = 32/16
#pragma unroll
        for (int ii = 0; ii < 8; ii++) {
            int d = tid + ii * 256;
            const float4* Bp = (const float4*)(lB + ((size_t)e * DMODEL + d) * 16);
            float s = 0.f;
#pragma unroll
            for (int q = 0; q < 4; q++) {
                float4 bv = Bp[q];
                s += bv.x * hs[q * 4 + 0] + bv.y * hs[q * 4 + 1]
                   + bv.z * hs[q * 4 + 2] + bv.w * hs[q * 4 + 3];
            }
            acc[ii] += wl * s;
        }
    }
#pragma unroll
    for (int ii = 0; ii < 8; ii++) {
        int d = tid + ii * 256;
        out[(size_t)t * DMODEL + d] += acc[ii];
    }
}

extern "C" void kernel_launch(void* const* d_in, const int* in_sizes, int n_in,
                              void* d_out, int out_size, void* d_ws, size_t ws_size,
                              hipStream_t stream) {
    const float* hidden = (const float*)d_in[0];
    const float* cosb   = (const float*)d_in[1];
    const float* sinb   = (const float*)d_in[2];
    const float* Wq     = (const float*)d_in[3];
    const float* Wk     = (const float*)d_in[4];
    const float* Wv     = (const float*)d_in[5];
    const float* Wo     = (const float*)d_in[6];
    const float* qnw    = (const float*)d_in[7];
    const float* knw    = (const float*)d_in[8];
    const float* gw     = (const float*)d_in[9];
    const float* lA     = (const float*)d_in[10];
    const float* lB     = (const float*)d_in[11];
    float* out = (float*)d_out;

    // workspace layout (~126 MB)
    char* ws = (char*)d_ws;
    __hip_bfloat16* hid_bf  = (__hip_bfloat16*)ws;                    // 8388608 el
    __hip_bfloat16* wqkv_bf = hid_bf + 8388608;                       // 8388608 el
    __hip_bfloat16* wo_bf   = wqkv_bf + 8388608;                      // 4194304 el
    float*          qkv     = (float*)(wo_bf + 4194304);              // 16777216 el
    __hip_bfloat16* attn_bf = (__hip_bfloat16*)(qkv + 16777216);      // 8388608 el
    float*          ew      = (float*)(attn_bf + 8388608);            // 16384 el

    // 1. casts
    cast_kernel<<<8192, 256, 0, stream>>>(hidden, hid_bf, 2097152);
    cast_kernel<<<4096, 256, 0, stream>>>(Wq, wqkv_bf,            1048576);
    cast_kernel<<<2048, 256, 0, stream>>>(Wk, wqkv_bf + 4194304,  524288);
    cast_kernel<<<2048, 256, 0, stream>>>(Wv, wqkv_bf + 6291456,  524288);
    cast_kernel<<<4096, 256, 0, stream>>>(Wo, wo_bf,              1048576);

    // 2. gate
    gate_kernel<<<4096, 256, 0, stream>>>(hidden, gw, ew);

    // 3. fused QKV projection (M=4096, N=4096, K=2048)
    gemm_bt<<<dim3(32, 32), 256, 0, stream>>>((const ushort*)hid_bf, (const ushort*)wqkv_bf,
                                              qkv, NTOK, QKV_CH, DMODEL);

    // 4. RMSNorm + RoPE in place
    normrope_kernel<<<24576, 256, 0, stream>>>(qkv, cosb, sinb, qnw, knw);

    // 5. attention -> attn_out (bf16)
    attn_kernel<<<16384, 256, 0, stream>>>(qkv, attn_bf);

    // 6. output projection (M=4096, N=2048, K=2048) -> d_out (fp32 base)
    gemm_bt<<<dim3(16, 32), 256, 0, stream>>>((const ushort*)attn_bf, (const ushort*)wo_bf,
                                              out, NTOK, DMODEL, NHEADS * HEADD);

    // 7. LoRA expert correction, += into d_out
    lora_kernel<<<4096, 256, 0, stream>>>(attn_bf, lA, lB, ew, out);
}

// Round 2
// 531.263 us; speedup vs baseline: 4.2180x; 4.2180x over previous
//
#include <hip/hip_runtime.h>
#include <hip/hip_bf16.h>

// Problem constants
#define S_LEN   1024
#define BATCH   4
#define DMODEL  2048
#define NHEADS  16
#define NKVH    8
#define HEADD   128
#define NTOK    4096      // BATCH*S_LEN
#define QKV_CH  4096      // 2048 q + 1024 k + 1024 v

typedef __bf16 bf16x8 __attribute__((ext_vector_type(8)));
typedef float  f32x4  __attribute__((ext_vector_type(4)));

__device__ __forceinline__ float bf2f(unsigned short u) {
    return __uint_as_float(((unsigned)u) << 16);
}
__device__ __forceinline__ ushort f2bu(float f) {
    union { __hip_bfloat16 h; ushort u; } c;
    c.h = __float2bfloat16(f);
    return c.u;
}

// ---------------- fp32 -> bf16 cast, 4 elems/thread ----------------
__global__ __launch_bounds__(256) void cast_kernel(const float* __restrict__ in,
                                                   __hip_bfloat16* __restrict__ out, int n4) {
    int i = blockIdx.x * 256 + threadIdx.x;
    if (i >= n4) return;
    float4 v = ((const float4*)in)[i];
    union { ushort4 u; __hip_bfloat16 h[4]; } r;
    r.h[0] = __float2bfloat16(v.x);
    r.h[1] = __float2bfloat16(v.y);
    r.h[2] = __float2bfloat16(v.z);
    r.h[3] = __float2bfloat16(v.w);
    ((ushort4*)out)[i] = r.u;
}

// ---------------- gate: logits -> softmax -> top2 -> dense expert weights ----------------
__global__ __launch_bounds__(256) void gate_kernel(const float* __restrict__ X,
                                                   const float* __restrict__ GW,
                                                   float* __restrict__ EW) {
    __shared__ float red[4][257];
    const int t = blockIdx.x, tid = threadIdx.x;
    const float* x = X + (size_t)t * DMODEL;
    float p0 = 0.f, p1 = 0.f, p2 = 0.f, p3 = 0.f;
    for (int d = tid; d < DMODEL; d += 256) {
        float xv = x[d];
        p0 += xv * GW[d];
        p1 += xv * GW[DMODEL + d];
        p2 += xv * GW[2 * DMODEL + d];
        p3 += xv * GW[3 * DMODEL + d];
    }
    red[0][tid] = p0; red[1][tid] = p1; red[2][tid] = p2; red[3][tid] = p3;
    __syncthreads();
    for (int s = 128; s > 0; s >>= 1) {
        if (tid < s) {
            red[0][tid] += red[0][tid + s];
            red[1][tid] += red[1][tid + s];
            red[2][tid] += red[2][tid + s];
            red[3][tid] += red[3][tid + s];
        }
        __syncthreads();
    }
    if (tid == 0) {
        float l[4] = { red[0][0], red[1][0], red[2][0], red[3][0] };
        float mx = fmaxf(fmaxf(l[0], l[1]), fmaxf(l[2], l[3]));
        float pe[4], sum = 0.f;
        for (int e = 0; e < 4; e++) { pe[e] = __expf(l[e] - mx); sum += pe[e]; }
        float inv = 1.0f / sum;
        for (int e = 0; e < 4; e++) pe[e] *= inv;
        int i1 = 0;
        for (int e = 1; e < 4; e++) if (pe[e] > pe[i1]) i1 = e;
        int i2 = -1;
        for (int e = 0; e < 4; e++) if (e != i1 && (i2 < 0 || pe[e] > pe[i2])) i2 = e;
        float o[4] = {0.f, 0.f, 0.f, 0.f};
        o[i1] = pe[i1]; o[i2] = pe[i2];
        float* ew = EW + (size_t)t * 4;
        ew[0] = o[0]; ew[1] = o[1]; ew[2] = o[2]; ew[3] = o[3];
    }
}

// ---------------- bf16 MFMA GEMM: C[M][N] = A[M][K] * B[N][K]^T ----------------
__global__ __launch_bounds__(256) void gemm_bt(const ushort* __restrict__ A,
                                               const ushort* __restrict__ B,
                                               float* __restrict__ C,
                                               int M, int N, int K) {
    __shared__ ushort As[128 * 32];
    __shared__ ushort Bs[128 * 32];
    const int tid  = threadIdx.x;
    const int wave = tid >> 6, lane = tid & 63;
    const int l16  = lane & 15, quad = lane >> 4;
    const int m0 = blockIdx.y * 128, n0 = blockIdx.x * 128;
    const int wm = (wave >> 1) * 64, wn = (wave & 1) * 64;

    f32x4 acc[4][4];
#pragma unroll
    for (int i = 0; i < 4; i++)
#pragma unroll
        for (int j = 0; j < 4; j++) acc[i][j] = (f32x4){0.f, 0.f, 0.f, 0.f};

    for (int k0 = 0; k0 < K; k0 += 32) {
        __syncthreads();
#pragma unroll
        for (int c0 = 0; c0 < 512; c0 += 256) {
            int c = c0 + tid;
            int row = c >> 2, kg = c & 3;
            ((uint4*)As)[c] = *(const uint4*)(A + (size_t)(m0 + row) * K + k0 + kg * 8);
            ((uint4*)Bs)[c] = *(const uint4*)(B + (size_t)(n0 + row) * K + k0 + kg * 8);
        }
        __syncthreads();
        bf16x8 af[4], bfr[4];
#pragma unroll
        for (int i = 0; i < 4; i++) {
            af[i]  = *(const bf16x8*)(As + (wm + i * 16 + l16) * 32 + quad * 8);
            bfr[i] = *(const bf16x8*)(Bs + (wn + i * 16 + l16) * 32 + quad * 8);
        }
#pragma unroll
        for (int i = 0; i < 4; i++)
#pragma unroll
            for (int j = 0; j < 4; j++)
                acc[i][j] = __builtin_amdgcn_mfma_f32_16x16x32_bf16(af[i], bfr[j], acc[i][j], 0, 0, 0);
    }
#pragma unroll
    for (int i = 0; i < 4; i++)
#pragma unroll
        for (int j = 0; j < 4; j++)
#pragma unroll
            for (int r = 0; r < 4; r++) {
                int m = m0 + wm + i * 16 + quad * 4 + r;
                int n = n0 + wn + j * 16 + l16;
                C[(size_t)m * N + n] = acc[i][j][r];
            }
}

// ---------------- RMSNorm + RoPE: fp32 qkv -> bf16 Qb[b,h,s,d] (scaled), Kb[b,kv,s,d] ----------------
__global__ __launch_bounds__(256) void normrope_kernel(const float* __restrict__ QKV,
                                                       const float* __restrict__ cosb,
                                                       const float* __restrict__ sinb,
                                                       const float* __restrict__ qw,
                                                       const float* __restrict__ kw,
                                                       ushort* __restrict__ Qb,
                                                       ushort* __restrict__ Kb) {
    const int wave = threadIdx.x >> 6, lane = threadIdx.x & 63;
    const int r = blockIdx.x * 4 + wave;
    const float* p; const float* w; int t; ushort* dst; float scale;
    if (r < NTOK * NHEADS) {
        t = r >> 4;
        int h = r & 15;
        p = QKV + (size_t)t * QKV_CH + h * HEADD;
        w = qw; scale = 0.08838834764831845f;   // 128^-0.5 folded into Q
        int b = t >> 10, s = t & 1023;
        dst = Qb + ((size_t)((b * 16 + h) * 1024 + s)) * HEADD;
    } else {
        int r2 = r - NTOK * NHEADS;
        t = r2 >> 3;
        int kv = r2 & 7;
        p = QKV + (size_t)t * QKV_CH + 2048 + kv * HEADD;
        w = kw; scale = 1.0f;
        int b = t >> 10, s = t & 1023;
        dst = Kb + ((size_t)((b * 8 + kv) * 1024 + s)) * HEADD;
    }
    float xl = p[lane], xh = p[lane + 64];
    float ss = xl * xl + xh * xh;
#pragma unroll
    for (int mask = 1; mask < 64; mask <<= 1) ss += __shfl_xor(ss, mask);
    float rstd = rsqrtf(ss * (1.0f / 128.0f) + 1e-6f);
    float nl = xl * rstd * w[lane];
    float nh = xh * rstd * w[lane + 64];
    const float* cp = cosb + (size_t)t * HEADD;
    const float* sp = sinb + (size_t)t * HEADD;
    float ol = nl * cp[lane]      - nh * sp[lane];
    float oh = nh * cp[lane + 64] + nl * sp[lane + 64];
    dst[lane]      = f2bu(ol * scale);
    dst[lane + 64] = f2bu(oh * scale);
}

// ---------------- V transpose: fp32 qkv v -> bf16 Vt[b,kv,d,s] ----------------
__global__ __launch_bounds__(256) void vtrans_kernel(const float* __restrict__ QKV,
                                                     ushort* __restrict__ Vt) {
    __shared__ float Ts[64][129];
    const int blk = blockIdx.x;          // 4*8*16
    const int sc = blk & 15;
    const int kvb = blk >> 4;            // b*8+kv
    const int s0 = sc * 64;
    const float* src = QKV + ((size_t)((kvb >> 3) * 1024 + s0)) * QKV_CH + 3072 + (kvb & 7) * HEADD;
    for (int c = threadIdx.x; c < 2048; c += 256) {
        int s = c >> 5, d0 = (c & 31) * 4;
        float4 v = *(const float4*)(src + (size_t)s * QKV_CH + d0);
        Ts[s][d0] = v.x; Ts[s][d0 + 1] = v.y; Ts[s][d0 + 2] = v.z; Ts[s][d0 + 3] = v.w;
    }
    __syncthreads();
    ushort* dst = Vt + ((size_t)kvb * HEADD) * S_LEN + s0;
    for (int c = threadIdx.x; c < 1024; c += 256) {
        int d = c >> 3, s8 = (c & 7) * 8;
        union { ushort u[8]; uint4 v; } pk;
#pragma unroll
        for (int j = 0; j < 8; j++) pk.u[j] = f2bu(Ts[s8 + j][d]);
        *(uint4*)(dst + (size_t)d * S_LEN + s8) = pk.v;
    }
}

// ---------------- flash attention (bf16 MFMA, online softmax) ----------------
// block = 64 queries of one (b,h); 4 waves x 16 q-rows; K-tiles of 64 keys.
#define KPITCH 136
#define VPITCH 72
__global__ __launch_bounds__(256) void fattn_kernel(const ushort* __restrict__ Qb,
                                                    const ushort* __restrict__ Kb,
                                                    const ushort* __restrict__ Vt,
                                                    __hip_bfloat16* __restrict__ O) {
    __shared__ __align__(16) ushort Ks[64 * KPITCH];
    __shared__ __align__(16) ushort Vs[128 * VPITCH];
    __shared__ __align__(16) ushort Ps[4 * 16 * VPITCH];
    const int tid = threadIdx.x;
    const int wq = tid >> 6, lane = tid & 63;
    const int l16 = lane & 15, quad = lane >> 4;
    const int qblk = 15 - (blockIdx.x >> 6);    // heavy q-blocks first
    const int bh = blockIdx.x & 63;
    const int b = bh >> 4, h = bh & 15;
    const int kvb = b * 8 + (h >> 1);
    const int q0 = qblk * 64;
    const int qbase = q0 + wq * 16;

    // Q A-fragments (m = l16, k = kt*32 + quad*8)
    bf16x8 qf[4];
    const ushort* qrow = Qb + ((size_t)bh * S_LEN + qbase + l16) * HEADD;
#pragma unroll
    for (int kt = 0; kt < 4; kt++)
        qf[kt] = *(const bf16x8*)(qrow + kt * 32 + quad * 8);

    f32x4 oacc[8];
#pragma unroll
    for (int dt = 0; dt < 8; dt++) oacc[dt] = (f32x4){0.f, 0.f, 0.f, 0.f};
    float m[4] = { -1e30f, -1e30f, -1e30f, -1e30f };
    float l[4] = { 0.f, 0.f, 0.f, 0.f };

    const ushort* kbase = Kb + (size_t)kvb * S_LEN * HEADD;
    const ushort* vbase = Vt + (size_t)kvb * HEADD * S_LEN;
    const int ntiles = qblk + 1;

    for (int kb = 0; kb < ntiles; kb++) {
        const int k0 = kb * 64;
        __syncthreads();
        // stage K tile: 64 keys x 128 d
        for (int c = tid; c < 1024; c += 256) {
            int row = c >> 4, col = (c & 15) * 8;
            *(uint4*)(Ks + row * KPITCH + col) =
                *(const uint4*)(kbase + (size_t)(k0 + row) * HEADD + col);
        }
        // stage V^T tile: 128 d x 64 keys
        for (int c = tid; c < 1024; c += 256) {
            int row = c >> 3, col = (c & 7) * 8;
            *(uint4*)(Vs + row * VPITCH + col) =
                *(const uint4*)(vbase + (size_t)row * S_LEN + k0 + col);
        }
        __syncthreads();

        // S = Q K^T : 4 n-tiles of 16 keys, 4 k-chunks of 32 over HD
        f32x4 sacc[4];
#pragma unroll
        for (int nt = 0; nt < 4; nt++) sacc[nt] = (f32x4){0.f, 0.f, 0.f, 0.f};
#pragma unroll
        for (int kt = 0; kt < 4; kt++) {
#pragma unroll
            for (int nt = 0; nt < 4; nt++) {
                bf16x8 kf = *(const bf16x8*)(Ks + (nt * 16 + l16) * KPITCH + kt * 32 + quad * 8);
                sacc[nt] = __builtin_amdgcn_mfma_f32_16x16x32_bf16(qf[kt], kf, sacc[nt], 0, 0, 0);
            }
        }

        // online softmax per q-row (row = quad*4 + r, key = k0 + nt*16 + l16)
        float alpha[4];
#pragma unroll
        for (int r = 0; r < 4; r++) {
            const int qg = qbase + quad * 4 + r;
            float sv[4], pb[4];
#pragma unroll
            for (int nt = 0; nt < 4; nt++) {
                int kg = k0 + nt * 16 + l16;
                sv[nt] = (kg <= qg) ? sacc[nt][r] : -1e30f;
            }
            float mx = fmaxf(fmaxf(sv[0], sv[1]), fmaxf(sv[2], sv[3]));
            mx = fmaxf(mx, __shfl_xor(mx, 1));
            mx = fmaxf(mx, __shfl_xor(mx, 2));
            mx = fmaxf(mx, __shfl_xor(mx, 4));
            mx = fmaxf(mx, __shfl_xor(mx, 8));
            float mn = fmaxf(m[r], mx);
            float al = __expf(m[r] - mn);
            m[r] = mn;
            float ps = 0.f;
#pragma unroll
            for (int nt = 0; nt < 4; nt++) {
                float p = __expf(sv[nt] - mn);
                pb[nt] = p; ps += p;
            }
            ps += __shfl_xor(ps, 1);
            ps += __shfl_xor(ps, 2);
            ps += __shfl_xor(ps, 4);
            ps += __shfl_xor(ps, 8);
            l[r] = l[r] * al + ps;
            alpha[r] = al;
            // P -> per-wave LDS (C layout -> A layout round trip)
#pragma unroll
            for (int nt = 0; nt < 4; nt++)
                Ps[wq * 16 * VPITCH + (quad * 4 + r) * VPITCH + nt * 16 + l16] = f2bu(pb[nt]);
        }
        // rescale O
#pragma unroll
        for (int dt = 0; dt < 8; dt++)
#pragma unroll
            for (int r = 0; r < 4; r++) oacc[dt][r] *= alpha[r];

        // O += P V : A = P (m=q), B = V^T rows (n=d)
#pragma unroll
        for (int kt2 = 0; kt2 < 2; kt2++) {
            bf16x8 pf = *(const bf16x8*)(Ps + wq * 16 * VPITCH + l16 * VPITCH + kt2 * 32 + quad * 8);
#pragma unroll
            for (int dt = 0; dt < 8; dt++) {
                bf16x8 vf = *(const bf16x8*)(Vs + (dt * 16 + l16) * VPITCH + kt2 * 32 + quad * 8);
                oacc[dt] = __builtin_amdgcn_mfma_f32_16x16x32_bf16(pf, vf, oacc[dt], 0, 0, 0);
            }
        }
    }

    // epilogue: O -> bf16 [b,s,h,d]
#pragma unroll
    for (int r = 0; r < 4; r++) {
        float inv = 1.0f / l[r];
        size_t base = ((size_t)(b * S_LEN + qbase + quad * 4 + r)) * (NHEADS * HEADD) + h * HEADD;
#pragma unroll
        for (int dt = 0; dt < 8; dt++)
            O[base + dt * 16 + l16] = __float2bfloat16(oacc[dt][r] * inv);
    }
}

// ---------------- LoRA MoE correction: out += sum_e w_e*2 * B_e (A_e x) ----------------
__global__ __launch_bounds__(256) void lora_kernel(const __hip_bfloat16* __restrict__ X,
                                                   const float* __restrict__ lA,
                                                   const float* __restrict__ lB,
                                                   const float* __restrict__ EW,
                                                   float* __restrict__ out) {
    __shared__ float xs[DMODEL];
    __shared__ float hred[16][17];
    __shared__ float hs[16];
    const int t = blockIdx.x, tid = threadIdx.x;

    const ushort4* src = (const ushort4*)(X + (size_t)t * DMODEL);
    for (int c = tid; c < 512; c += 256) {
        ushort4 u = src[c];
        xs[c * 4 + 0] = bf2f(u.x);
        xs[c * 4 + 1] = bf2f(u.y);
        xs[c * 4 + 2] = bf2f(u.z);
        xs[c * 4 + 3] = bf2f(u.w);
    }
    float ew[4] = { EW[(size_t)t * 4 + 0], EW[(size_t)t * 4 + 1],
                    EW[(size_t)t * 4 + 2], EW[(size_t)t * 4 + 3] };
    __syncthreads();

    float acc[8];
#pragma unroll
    for (int i = 0; i < 8; i++) acc[i] = 0.f;

    const int r = tid >> 4, g = tid & 15;
    for (int e = 0; e < 4; e++) {
        float w = ew[e];
        if (w == 0.f) continue;
        const float* Ar = lA + ((size_t)e * 16 + r) * DMODEL;
        float p = 0.f;
        for (int i = 0; i < 128; i++) {
            int d = g + (i << 4);
            p += xs[d] * Ar[d];
        }
        __syncthreads();
        hred[r][g] = p;
        __syncthreads();
        if (tid < 16) {
            float s = 0.f;
#pragma unroll
            for (int g2 = 0; g2 < 16; g2++) s += hred[tid][g2];
            hs[tid] = s;
        }
        __syncthreads();
        float wl = w * 2.0f;
#pragma unroll
        for (int ii = 0; ii < 8; ii++) {
            int d = tid + ii * 256;
            const float4* Bp = (const float4*)(lB + ((size_t)e * DMODEL + d) * 16);
            float s = 0.f;
#pragma unroll
            for (int q = 0; q < 4; q++) {
                float4 bv = Bp[q];
                s += bv.x * hs[q * 4 + 0] + bv.y * hs[q * 4 + 1]
                   + bv.z * hs[q * 4 + 2] + bv.w * hs[q * 4 + 3];
            }
            acc[ii] += wl * s;
        }
    }
#pragma unroll
    for (int ii = 0; ii < 8; ii++) {
        int d = tid + ii * 256;
        out[(size_t)t * DMODEL + d] += acc[ii];
    }
}

extern "C" void kernel_launch(void* const* d_in, const int* in_sizes, int n_in,
                              void* d_out, int out_size, void* d_ws, size_t ws_size,
                              hipStream_t stream) {
    const float* hidden = (const float*)d_in[0];
    const float* cosb   = (const float*)d_in[1];
    const float* sinb   = (const float*)d_in[2];
    const float* Wq     = (const float*)d_in[3];
    const float* Wk     = (const float*)d_in[4];
    const float* Wv     = (const float*)d_in[5];
    const float* Wo     = (const float*)d_in[6];
    const float* qnw    = (const float*)d_in[7];
    const float* knw    = (const float*)d_in[8];
    const float* gw     = (const float*)d_in[9];
    const float* lA     = (const float*)d_in[10];
    const float* lB     = (const float*)d_in[11];
    float* out = (float*)d_out;

    // workspace layout (~104 MB, with lifetime-based aliasing):
    //  [0,16M):    hid_bf (dead after QKV gemm)  -> Qb (written by normrope)
    //  [16M,32M):  wqkv_bf (dead after QKV gemm) -> Kb (8M) + Vt (8M)
    //  [32M,40M):  wo_bf
    //  [40M,104M): qkv fp32 (dead after vtrans)  -> attn_bf (16M)
    //  [104M,+):   ew
    char* ws = (char*)d_ws;
    __hip_bfloat16* hid_bf  = (__hip_bfloat16*)ws;
    __hip_bfloat16* wqkv_bf = (__hip_bfloat16*)(ws + (16u << 20));
    __hip_bfloat16* wo_bf   = (__hip_bfloat16*)(ws + (32u << 20));
    float*          qkv     = (float*)(ws + (40u << 20));
    float*          ew      = (float*)(ws + (104u << 20));
    ushort*         Qb      = (ushort*)ws;                     // alias hid_bf
    ushort*         Kb      = (ushort*)(ws + (16u << 20));     // alias wqkv_bf[0:8M)
    ushort*         Vt      = (ushort*)(ws + (24u << 20));     // alias wqkv_bf[8M:16M)
    __hip_bfloat16* attn_bf = (__hip_bfloat16*)(ws + (40u << 20)); // alias qkv

    // 1. casts
    cast_kernel<<<8192, 256, 0, stream>>>(hidden, hid_bf, 2097152);
    cast_kernel<<<4096, 256, 0, stream>>>(Wq, wqkv_bf,            1048576);
    cast_kernel<<<2048, 256, 0, stream>>>(Wk, wqkv_bf + 4194304,  524288);
    cast_kernel<<<2048, 256, 0, stream>>>(Wv, wqkv_bf + 6291456,  524288);
    cast_kernel<<<4096, 256, 0, stream>>>(Wo, wo_bf,              1048576);

    // 2. gate
    gate_kernel<<<4096, 256, 0, stream>>>(hidden, gw, ew);

    // 3. fused QKV projection (M=4096, N=4096, K=2048) -> fp32 qkv
    gemm_bt<<<dim3(32, 32), 256, 0, stream>>>((const ushort*)hid_bf, (const ushort*)wqkv_bf,
                                              qkv, NTOK, QKV_CH, DMODEL);

    // 4. RMSNorm + RoPE -> bf16 Qb (scaled), Kb ; V transpose -> Vt
    normrope_kernel<<<24576, 256, 0, stream>>>(qkv, cosb, sinb, qnw, knw, Qb, Kb);
    vtrans_kernel<<<512, 256, 0, stream>>>(qkv, Vt);

    // 5. flash attention -> attn_bf
    fattn_kernel<<<1024, 256, 0, stream>>>(Qb, Kb, Vt, attn_bf);

    // 6. output projection (M=4096, N=2048, K=2048) -> d_out (fp32 base)
    gemm_bt<<<dim3(16, 32), 256, 0, stream>>>((const ushort*)attn_bf, (const ushort*)wo_bf,
                                              out, NTOK, DMODEL, NHEADS * HEADD);

    // 7. LoRA expert correction, += into d_out
    lora_kernel<<<4096, 256, 0, stream>>>(attn_bf, lA, lB, ew, out);
}

// Round 4
// 439.497 us; speedup vs baseline: 5.0987x; 1.2088x over previous
//
#include <hip/hip_runtime.h>
#include <hip/hip_bf16.h>

// Problem constants
#define S_LEN   1024
#define BATCH   4
#define DMODEL  2048
#define NHEADS  16
#define NKVH    8
#define HEADD   128
#define NTOK    4096      // BATCH*S_LEN
#define QKV_CH  4096      // 2048 q + 1024 k + 1024 v

typedef __bf16 bf16x8 __attribute__((ext_vector_type(8)));
typedef float  f32x4  __attribute__((ext_vector_type(4)));

__device__ __forceinline__ float bf2f(unsigned short u) {
    return __uint_as_float(((unsigned)u) << 16);
}
__device__ __forceinline__ ushort f2bu(float f) {
    union { __hip_bfloat16 h; ushort u; } c;
    c.h = __float2bfloat16(f);
    return c.u;
}
// async global->LDS, 16B per lane; LDS dest must be wave-contiguous in lane order
__device__ __forceinline__ void gl_lds16(const ushort* g, ushort* l) {
    __builtin_amdgcn_global_load_lds(
        (const __attribute__((address_space(1))) void*)g,
        (__attribute__((address_space(3))) void*)l,
        16, 0, 0);
}

// ---------------- fp32 -> bf16 cast, 4 elems/thread ----------------
__global__ __launch_bounds__(256) void cast_kernel(const float* __restrict__ in,
                                                   __hip_bfloat16* __restrict__ out, int n4) {
    int i = blockIdx.x * 256 + threadIdx.x;
    if (i >= n4) return;
    float4 v = ((const float4*)in)[i];
    union { ushort4 u; __hip_bfloat16 h[4]; } r;
    r.h[0] = __float2bfloat16(v.x);
    r.h[1] = __float2bfloat16(v.y);
    r.h[2] = __float2bfloat16(v.z);
    r.h[3] = __float2bfloat16(v.w);
    ((ushort4*)out)[i] = r.u;
}

// ---------------- lB (e,d,r) fp32 -> Bt[d][e*16+r] bf16 ----------------
__global__ __launch_bounds__(256) void btrans_kernel(const float* __restrict__ lB,
                                                     ushort* __restrict__ Bt) {
    int idx = blockIdx.x * 256 + threadIdx.x;   // 131072
    int d = idx >> 6, er = idx & 63;
    int e = er >> 4, r = er & 15;
    Bt[idx] = f2bu(lB[((size_t)e * DMODEL + d) * 16 + r]);
}

// ---------------- gate: logits -> softmax -> top2 -> dense expert weights ----------------
__global__ __launch_bounds__(256) void gate_kernel(const float* __restrict__ X,
                                                   const float* __restrict__ GW,
                                                   float* __restrict__ EW) {
    __shared__ float red[4][257];
    const int t = blockIdx.x, tid = threadIdx.x;
    const float* x = X + (size_t)t * DMODEL;
    float p0 = 0.f, p1 = 0.f, p2 = 0.f, p3 = 0.f;
    for (int d = tid; d < DMODEL; d += 256) {
        float xv = x[d];
        p0 += xv * GW[d];
        p1 += xv * GW[DMODEL + d];
        p2 += xv * GW[2 * DMODEL + d];
        p3 += xv * GW[3 * DMODEL + d];
    }
    red[0][tid] = p0; red[1][tid] = p1; red[2][tid] = p2; red[3][tid] = p3;
    __syncthreads();
    for (int s = 128; s > 0; s >>= 1) {
        if (tid < s) {
            red[0][tid] += red[0][tid + s];
            red[1][tid] += red[1][tid + s];
            red[2][tid] += red[2][tid + s];
            red[3][tid] += red[3][tid + s];
        }
        __syncthreads();
    }
    if (tid == 0) {
        float l[4] = { red[0][0], red[1][0], red[2][0], red[3][0] };
        float mx = fmaxf(fmaxf(l[0], l[1]), fmaxf(l[2], l[3]));
        float pe[4], sum = 0.f;
        for (int e = 0; e < 4; e++) { pe[e] = __expf(l[e] - mx); sum += pe[e]; }
        float inv = 1.0f / sum;
        for (int e = 0; e < 4; e++) pe[e] *= inv;
        int i1 = 0;
        for (int e = 1; e < 4; e++) if (pe[e] > pe[i1]) i1 = e;
        int i2 = -1;
        for (int e = 0; e < 4; e++) if (e != i1 && (i2 < 0 || pe[e] > pe[i2])) i2 = e;
        float o[4] = {0.f, 0.f, 0.f, 0.f};
        o[i1] = pe[i1]; o[i2] = pe[i2];
        float* ew = EW + (size_t)t * 4;
        ew[0] = o[0]; ew[1] = o[1]; ew[2] = o[2]; ew[3] = o[3];
    }
}

// ---------------- bf16 MFMA GEMM: C[M][N] = A[M][K] * B[N][K]^T ----------------
// 128x128 tile, 4 waves, global_load_lds staging (m97 structure).
__global__ __launch_bounds__(256) void gemm_bt(const ushort* __restrict__ A,
                                               const ushort* __restrict__ B,
                                               float* __restrict__ C,
                                               int M, int N, int K) {
    __shared__ ushort As[128 * 32];
    __shared__ ushort Bs[128 * 32];
    const int tid  = threadIdx.x;
    const int wave = tid >> 6, lane = tid & 63;
    const int l16  = lane & 15, quad = lane >> 4;
    const int m0 = blockIdx.y * 128, n0 = blockIdx.x * 128;
    const int wm = (wave >> 1) * 64, wn = (wave & 1) * 64;

    f32x4 acc[4][4];
#pragma unroll
    for (int i = 0; i < 4; i++)
#pragma unroll
        for (int j = 0; j < 4; j++) acc[i][j] = (f32x4){0.f, 0.f, 0.f, 0.f};

    const int r1 = tid >> 2, kg1 = (tid & 3) * 8;
    const int r2 = (tid + 256) >> 2, kg2 = ((tid + 256) & 3) * 8;

    for (int k0 = 0; k0 < K; k0 += 32) {
        __syncthreads();
        gl_lds16(A + (size_t)(m0 + r1) * K + k0 + kg1, As + tid * 8);
        gl_lds16(B + (size_t)(n0 + r1) * K + k0 + kg1, Bs + tid * 8);
        gl_lds16(A + (size_t)(m0 + r2) * K + k0 + kg2, As + (tid + 256) * 8);
        gl_lds16(B + (size_t)(n0 + r2) * K + k0 + kg2, Bs + (tid + 256) * 8);
        __syncthreads();
        bf16x8 af[4], bfr[4];
#pragma unroll
        for (int i = 0; i < 4; i++) {
            af[i]  = *(const bf16x8*)(As + (wm + i * 16 + l16) * 32 + quad * 8);
            bfr[i] = *(const bf16x8*)(Bs + (wn + i * 16 + l16) * 32 + quad * 8);
        }
#pragma unroll
        for (int i = 0; i < 4; i++)
#pragma unroll
            for (int j = 0; j < 4; j++)
                acc[i][j] = __builtin_amdgcn_mfma_f32_16x16x32_bf16(af[i], bfr[j], acc[i][j], 0, 0, 0);
    }
#pragma unroll
    for (int i = 0; i < 4; i++)
#pragma unroll
        for (int j = 0; j < 4; j++)
#pragma unroll
            for (int r = 0; r < 4; r++) {
                int m = m0 + wm + i * 16 + quad * 4 + r;
                int n = n0 + wn + j * 16 + l16;
                C[(size_t)m * N + n] = acc[i][j][r];
            }
}

// ---------------- Wo GEMM with fused LoRA delta: C = A*B^T + A2*B2^T ----------------
// A: M x 2048 (attn bf16), B: 2048 x 2048 (Wo bf16), A2: M x 64 (G), B2: 2048 x 64 (Bt)
__global__ __launch_bounds__(256) void gemm_bt_lora(const ushort* __restrict__ A,
                                                    const ushort* __restrict__ B,
                                                    const ushort* __restrict__ A2,
                                                    const ushort* __restrict__ B2,
                                                    float* __restrict__ C) {
    __shared__ ushort As[128 * 32];
    __shared__ ushort Bs[128 * 32];
    const int tid  = threadIdx.x;
    const int wave = tid >> 6, lane = tid & 63;
    const int l16  = lane & 15, quad = lane >> 4;
    const int m0 = blockIdx.y * 128, n0 = blockIdx.x * 128;
    const int wm = (wave >> 1) * 64, wn = (wave & 1) * 64;
    const int K = DMODEL, N = DMODEL;

    f32x4 acc[4][4];
#pragma unroll
    for (int i = 0; i < 4; i++)
#pragma unroll
        for (int j = 0; j < 4; j++) acc[i][j] = (f32x4){0.f, 0.f, 0.f, 0.f};

    const int r1 = tid >> 2, kg1 = (tid & 3) * 8;
    const int r2 = (tid + 256) >> 2, kg2 = ((tid + 256) & 3) * 8;

    for (int k0 = 0; k0 < K; k0 += 32) {
        __syncthreads();
        gl_lds16(A + (size_t)(m0 + r1) * K + k0 + kg1, As + tid * 8);
        gl_lds16(B + (size_t)(n0 + r1) * K + k0 + kg1, Bs + tid * 8);
        gl_lds16(A + (size_t)(m0 + r2) * K + k0 + kg2, As + (tid + 256) * 8);
        gl_lds16(B + (size_t)(n0 + r2) * K + k0 + kg2, Bs + (tid + 256) * 8);
        __syncthreads();
        bf16x8 af[4], bfr[4];
#pragma unroll
        for (int i = 0; i < 4; i++) {
            af[i]  = *(const bf16x8*)(As + (wm + i * 16 + l16) * 32 + quad * 8);
            bfr[i] = *(const bf16x8*)(Bs + (wn + i * 16 + l16) * 32 + quad * 8);
        }
#pragma unroll
        for (int i = 0; i < 4; i++)
#pragma unroll
            for (int j = 0; j < 4; j++)
                acc[i][j] = __builtin_amdgcn_mfma_f32_16x16x32_bf16(af[i], bfr[j], acc[i][j], 0, 0, 0);
    }

    // LoRA delta: 2 extra K-steps over K2=64 (A2 stride 64, B2 stride 64)
#pragma unroll
    for (int k0 = 0; k0 < 64; k0 += 32) {
        __syncthreads();
        gl_lds16(A2 + (size_t)(m0 + r1) * 64 + k0 + kg1, As + tid * 8);
        gl_lds16(B2 + (size_t)(n0 + r1) * 64 + k0 + kg1, Bs + tid * 8);
        gl_lds16(A2 + (size_t)(m0 + r2) * 64 + k0 + kg2, As + (tid + 256) * 8);
        gl_lds16(B2 + (size_t)(n0 + r2) * 64 + k0 + kg2, Bs + (tid + 256) * 8);
        __syncthreads();
        bf16x8 af[4], bfr[4];
#pragma unroll
        for (int i = 0; i < 4; i++) {
            af[i]  = *(const bf16x8*)(As + (wm + i * 16 + l16) * 32 + quad * 8);
            bfr[i] = *(const bf16x8*)(Bs + (wn + i * 16 + l16) * 32 + quad * 8);
        }
#pragma unroll
        for (int i = 0; i < 4; i++)
#pragma unroll
            for (int j = 0; j < 4; j++)
                acc[i][j] = __builtin_amdgcn_mfma_f32_16x16x32_bf16(af[i], bfr[j], acc[i][j], 0, 0, 0);
    }

#pragma unroll
    for (int i = 0; i < 4; i++)
#pragma unroll
        for (int j = 0; j < 4; j++)
#pragma unroll
            for (int r = 0; r < 4; r++) {
                int m = m0 + wm + i * 16 + quad * 4 + r;
                int n = n0 + wn + j * 16 + l16;
                C[(size_t)m * N + n] = acc[i][j][r];
            }
}

// ---------------- LoRA H: G[t][e*16+r] = bf16(2*ew[t][e] * (x_t . A[e][r])) ----------------
// M-tile 64 (4 waves x 16 rows), N=64, K=2048.
__global__ __launch_bounds__(256) void lora_h_kernel(const ushort* __restrict__ X,
                                                     const ushort* __restrict__ Acat,
                                                     const float* __restrict__ EW,
                                                     ushort* __restrict__ G) {
    __shared__ ushort As[64 * 32];
    __shared__ ushort Bs[64 * 32];
    const int tid = threadIdx.x;
    const int wave = tid >> 6, lane = tid & 63;
    const int l16 = lane & 15, quad = lane >> 4;
    const int m0 = blockIdx.x * 64;

    f32x4 acc[4];
#pragma unroll
    for (int nt = 0; nt < 4; nt++) acc[nt] = (f32x4){0.f, 0.f, 0.f, 0.f};

    const int r1 = tid >> 2, kg1 = (tid & 3) * 8;

    for (int k0 = 0; k0 < DMODEL; k0 += 32) {
        __syncthreads();
        gl_lds16(X + (size_t)(m0 + r1) * DMODEL + k0 + kg1, As + tid * 8);
        gl_lds16(Acat + (size_t)r1 * DMODEL + k0 + kg1, Bs + tid * 8);
        __syncthreads();
        bf16x8 af = *(const bf16x8*)(As + (wave * 16 + l16) * 32 + quad * 8);
#pragma unroll
        for (int nt = 0; nt < 4; nt++) {
            bf16x8 bfr = *(const bf16x8*)(Bs + (nt * 16 + l16) * 32 + quad * 8);
            acc[nt] = __builtin_amdgcn_mfma_f32_16x16x32_bf16(af, bfr, acc[nt], 0, 0, 0);
        }
    }
#pragma unroll
    for (int nt = 0; nt < 4; nt++)
#pragma unroll
        for (int r = 0; r < 4; r++) {
            int m = m0 + wave * 16 + quad * 4 + r;
            float wsc = 2.0f * EW[(size_t)m * 4 + nt];   // LORA_SCALE=2 folded
            G[(size_t)m * 64 + nt * 16 + l16] = f2bu(acc[nt][r] * wsc);
        }
}

// ---------------- RMSNorm + RoPE: fp32 qkv -> bf16 Qb[b,h,s,d] (scaled), Kb[b,kv,s,d] ----------------
__global__ __launch_bounds__(256) void normrope_kernel(const float* __restrict__ QKV,
                                                       const float* __restrict__ cosb,
                                                       const float* __restrict__ sinb,
                                                       const float* __restrict__ qw,
                                                       const float* __restrict__ kw,
                                                       ushort* __restrict__ Qb,
                                                       ushort* __restrict__ Kb) {
    const int wave = threadIdx.x >> 6, lane = threadIdx.x & 63;
    const int r = blockIdx.x * 4 + wave;
    const float* p; const float* w; int t; ushort* dst; float scale;
    if (r < NTOK * NHEADS) {
        t = r >> 4;
        int h = r & 15;
        p = QKV + (size_t)t * QKV_CH + h * HEADD;
        w = qw; scale = 0.08838834764831845f;   // 128^-0.5 folded into Q
        int b = t >> 10, s = t & 1023;
        dst = Qb + ((size_t)((b * 16 + h) * 1024 + s)) * HEADD;
    } else {
        int r2 = r - NTOK * NHEADS;
        t = r2 >> 3;
        int kv = r2 & 7;
        p = QKV + (size_t)t * QKV_CH + 2048 + kv * HEADD;
        w = kw; scale = 1.0f;
        int b = t >> 10, s = t & 1023;
        dst = Kb + ((size_t)((b * 8 + kv) * 1024 + s)) * HEADD;
    }
    float xl = p[lane], xh = p[lane + 64];
    float ss = xl * xl + xh * xh;
#pragma unroll
    for (int mask = 1; mask < 64; mask <<= 1) ss += __shfl_xor(ss, mask);
    float rstd = rsqrtf(ss * (1.0f / 128.0f) + 1e-6f);
    float nl = xl * rstd * w[lane];
    float nh = xh * rstd * w[lane + 64];
    const float* cp = cosb + (size_t)t * HEADD;
    const float* sp = sinb + (size_t)t * HEADD;
    float ol = nl * cp[lane]      - nh * sp[lane];
    float oh = nh * cp[lane + 64] + nl * sp[lane + 64];
    dst[lane]      = f2bu(ol * scale);
    dst[lane + 64] = f2bu(oh * scale);
}

// ---------------- V transpose: fp32 qkv v -> bf16 Vt[b,kv,d,s] ----------------
__global__ __launch_bounds__(256) void vtrans_kernel(const float* __restrict__ QKV,
                                                     ushort* __restrict__ Vt) {
    __shared__ float Ts[64][129];
    const int blk = blockIdx.x;          // 4*8*16
    const int sc = blk & 15;
    const int kvb = blk >> 4;            // b*8+kv
    const int s0 = sc * 64;
    const float* src = QKV + ((size_t)((kvb >> 3) * 1024 + s0)) * QKV_CH + 3072 + (kvb & 7) * HEADD;
    for (int c = threadIdx.x; c < 2048; c += 256) {
        int s = c >> 5, d0 = (c & 31) * 4;
        float4 v = *(const float4*)(src + (size_t)s * QKV_CH + d0);
        Ts[s][d0] = v.x; Ts[s][d0 + 1] = v.y; Ts[s][d0 + 2] = v.z; Ts[s][d0 + 3] = v.w;
    }
    __syncthreads();
    ushort* dst = Vt + ((size_t)kvb * HEADD) * S_LEN + s0;
    for (int c = threadIdx.x; c < 1024; c += 256) {
        int d = c >> 3, s8 = (c & 7) * 8;
        union { ushort u[8]; uint4 v; } pk;
#pragma unroll
        for (int j = 0; j < 8; j++) pk.u[j] = f2bu(Ts[s8 + j][d]);
        *(uint4*)(dst + (size_t)d * S_LEN + s8) = pk.v;
    }
}

// ---------------- flash attention (bf16 MFMA, online softmax) ----------------
#define KPITCH 136
#define VPITCH 72
__global__ __launch_bounds__(256) void fattn_kernel(const ushort* __restrict__ Qb,
                                                    const ushort* __restrict__ Kb,
                                                    const ushort* __restrict__ Vt,
                                                    __hip_bfloat16* __restrict__ O) {
    __shared__ __align__(16) ushort Ks[64 * KPITCH];
    __shared__ __align__(16) ushort Vs[128 * VPITCH];
    __shared__ __align__(16) ushort Ps[4 * 16 * VPITCH];
    const int tid = threadIdx.x;
    const int wq = tid >> 6, lane = tid & 63;
    const int l16 = lane & 15, quad = lane >> 4;
    const int qblk = 15 - (blockIdx.x >> 6);    // heavy q-blocks first
    const int bh = blockIdx.x & 63;
    const int b = bh >> 4, h = bh & 15;
    const int kvb = b * 8 + (h >> 1);
    const int q0 = qblk * 64;
    const int qbase = q0 + wq * 16;

    bf16x8 qf[4];
    const ushort* qrow = Qb + ((size_t)bh * S_LEN + qbase + l16) * HEADD;
#pragma unroll
    for (int kt = 0; kt < 4; kt++)
        qf[kt] = *(const bf16x8*)(qrow + kt * 32 + quad * 8);

    f32x4 oacc[8];
#pragma unroll
    for (int dt = 0; dt < 8; dt++) oacc[dt] = (f32x4){0.f, 0.f, 0.f, 0.f};
    float m[4] = { -1e30f, -1e30f, -1e30f, -1e30f };
    float l[4] = { 0.f, 0.f, 0.f, 0.f };

    const ushort* kbase = Kb + (size_t)kvb * S_LEN * HEADD;
    const ushort* vbase = Vt + (size_t)kvb * HEADD * S_LEN;
    const int ntiles = qblk + 1;

    for (int kb = 0; kb < ntiles; kb++) {
        const int k0 = kb * 64;
        __syncthreads();
        for (int c = tid; c < 1024; c += 256) {
            int row = c >> 4, col = (c & 15) * 8;
            *(uint4*)(Ks + row * KPITCH + col) =
                *(const uint4*)(kbase + (size_t)(k0 + row) * HEADD + col);
        }
        for (int c = tid; c < 1024; c += 256) {
            int row = c >> 3, col = (c & 7) * 8;
            *(uint4*)(Vs + row * VPITCH + col) =
                *(const uint4*)(vbase + (size_t)row * S_LEN + k0 + col);
        }
        __syncthreads();

        f32x4 sacc[4];
#pragma unroll
        for (int nt = 0; nt < 4; nt++) sacc[nt] = (f32x4){0.f, 0.f, 0.f, 0.f};
#pragma unroll
        for (int kt = 0; kt < 4; kt++) {
#pragma unroll
            for (int nt = 0; nt < 4; nt++) {
                bf16x8 kf = *(const bf16x8*)(Ks + (nt * 16 + l16) * KPITCH + kt * 32 + quad * 8);
                sacc[nt] = __builtin_amdgcn_mfma_f32_16x16x32_bf16(qf[kt], kf, sacc[nt], 0, 0, 0);
            }
        }

        float alpha[4];
#pragma unroll
        for (int r = 0; r < 4; r++) {
            const int qg = qbase + quad * 4 + r;
            float sv[4], pb[4];
#pragma unroll
            for (int nt = 0; nt < 4; nt++) {
                int kg = k0 + nt * 16 + l16;
                sv[nt] = (kg <= qg) ? sacc[nt][r] : -1e30f;
            }
            float mx = fmaxf(fmaxf(sv[0], sv[1]), fmaxf(sv[2], sv[3]));
            mx = fmaxf(mx, __shfl_xor(mx, 1));
            mx = fmaxf(mx, __shfl_xor(mx, 2));
            mx = fmaxf(mx, __shfl_xor(mx, 4));
            mx = fmaxf(mx, __shfl_xor(mx, 8));
            float mn = fmaxf(m[r], mx);
            float al = __expf(m[r] - mn);
            m[r] = mn;
            float ps = 0.f;
#pragma unroll
            for (int nt = 0; nt < 4; nt++) {
                float p = __expf(sv[nt] - mn);
                pb[nt] = p; ps += p;
            }
            ps += __shfl_xor(ps, 1);
            ps += __shfl_xor(ps, 2);
            ps += __shfl_xor(ps, 4);
            ps += __shfl_xor(ps, 8);
            l[r] = l[r] * al + ps;
            alpha[r] = al;
#pragma unroll
            for (int nt = 0; nt < 4; nt++)
                Ps[wq * 16 * VPITCH + (quad * 4 + r) * VPITCH + nt * 16 + l16] = f2bu(pb[nt]);
        }
#pragma unroll
        for (int dt = 0; dt < 8; dt++)
#pragma unroll
            for (int r = 0; r < 4; r++) oacc[dt][r] *= alpha[r];

#pragma unroll
        for (int kt2 = 0; kt2 < 2; kt2++) {
            bf16x8 pf = *(const bf16x8*)(Ps + wq * 16 * VPITCH + l16 * VPITCH + kt2 * 32 + quad * 8);
#pragma unroll
            for (int dt = 0; dt < 8; dt++) {
                bf16x8 vf = *(const bf16x8*)(Vs + (dt * 16 + l16) * VPITCH + kt2 * 32 + quad * 8);
                oacc[dt] = __builtin_amdgcn_mfma_f32_16x16x32_bf16(pf, vf, oacc[dt], 0, 0, 0);
            }
        }
    }

#pragma unroll
    for (int r = 0; r < 4; r++) {
        float inv = 1.0f / l[r];
        size_t base = ((size_t)(b * S_LEN + qbase + quad * 4 + r)) * (NHEADS * HEADD) + h * HEADD;
#pragma unroll
        for (int dt = 0; dt < 8; dt++)
            O[base + dt * 16 + l16] = __float2bfloat16(oacc[dt][r] * inv);
    }
}

extern "C" void kernel_launch(void* const* d_in, const int* in_sizes, int n_in,
                              void* d_out, int out_size, void* d_ws, size_t ws_size,
                              hipStream_t stream) {
    const float* hidden = (const float*)d_in[0];
    const float* cosb   = (const float*)d_in[1];
    const float* sinb   = (const float*)d_in[2];
    const float* Wq     = (const float*)d_in[3];
    const float* Wk     = (const float*)d_in[4];
    const float* Wv     = (const float*)d_in[5];
    const float* Wo     = (const float*)d_in[6];
    const float* qnw    = (const float*)d_in[7];
    const float* knw    = (const float*)d_in[8];
    const float* gw     = (const float*)d_in[9];
    const float* lA     = (const float*)d_in[10];
    const float* lB     = (const float*)d_in[11];
    float* out = (float*)d_out;

    // workspace layout (~104 MB, lifetime-aliased):
    //  [0,16M):    hid_bf (dead after QKV gemm)  -> Qb
    //  [16M,32M):  wqkv_bf (dead after QKV gemm) -> Kb (8M) + Vt (8M)
    //  [32M,40M):  wo_bf
    //  [40M,104M): qkv fp32 (dead after vtrans)  -> attn_bf [40M,56M) + Acat/Bt/G @56M
    //  [104M,+64K): ew
    char* ws = (char*)d_ws;
    __hip_bfloat16* hid_bf  = (__hip_bfloat16*)ws;
    __hip_bfloat16* wqkv_bf = (__hip_bfloat16*)(ws + (16u << 20));
    __hip_bfloat16* wo_bf   = (__hip_bfloat16*)(ws + (32u << 20));
    float*          qkv     = (float*)(ws + (40u << 20));
    float*          ew      = (float*)(ws + (104u << 20));
    ushort*         Qb      = (ushort*)ws;
    ushort*         Kb      = (ushort*)(ws + (16u << 20));
    ushort*         Vt      = (ushort*)(ws + (24u << 20));
    __hip_bfloat16* attn_bf = (__hip_bfloat16*)(ws + (40u << 20));
    ushort*         Acat    = (ushort*)(ws + (56u << 20));              // 256 KB
    ushort*         Bt      = (ushort*)(ws + (56u << 20) + (256u << 10)); // 256 KB
    ushort*         G       = (ushort*)(ws + (56u << 20) + (512u << 10)); // 512 KB

    // 1. casts
    cast_kernel<<<8192, 256, 0, stream>>>(hidden, hid_bf, 2097152);
    cast_kernel<<<4096, 256, 0, stream>>>(Wq, wqkv_bf,            1048576);
    cast_kernel<<<2048, 256, 0, stream>>>(Wk, wqkv_bf + 4194304,  524288);
    cast_kernel<<<2048, 256, 0, stream>>>(Wv, wqkv_bf + 6291456,  524288);
    cast_kernel<<<4096, 256, 0, stream>>>(Wo, wo_bf,              1048576);

    // 2. gate
    gate_kernel<<<4096, 256, 0, stream>>>(hidden, gw, ew);

    // 3. fused QKV projection (M=4096, N=4096, K=2048) -> fp32 qkv
    gemm_bt<<<dim3(32, 32), 256, 0, stream>>>((const ushort*)hid_bf, (const ushort*)wqkv_bf,
                                              qkv, NTOK, QKV_CH, DMODEL);

    // 4. RMSNorm + RoPE -> Qb/Kb ; V transpose -> Vt (qkv dead after this)
    normrope_kernel<<<24576, 256, 0, stream>>>(qkv, cosb, sinb, qnw, knw, Qb, Kb);
    vtrans_kernel<<<512, 256, 0, stream>>>(qkv, Vt);

    // 5. LoRA weight prep (into dead qkv region — must follow vtrans)
    cast_kernel<<<128, 256, 0, stream>>>(lA, (__hip_bfloat16*)Acat, 32768);
    btrans_kernel<<<512, 256, 0, stream>>>(lB, Bt);

    // 6. flash attention -> attn_bf
    fattn_kernel<<<1024, 256, 0, stream>>>(Qb, Kb, Vt, attn_bf);

    // 7. LoRA H: G = 2*ew*(attn @ Acat^T)  (M=4096, N=64, K=2048)
    lora_h_kernel<<<64, 256, 0, stream>>>((const ushort*)attn_bf, Acat, ew, G);

    // 8. output projection + fused LoRA delta -> d_out
    gemm_bt_lora<<<dim3(16, 32), 256, 0, stream>>>((const ushort*)attn_bf, (const ushort*)wo_bf,
                                                   G, Bt, out);
}

// Round 5
// 432.034 us; speedup vs baseline: 5.1868x; 1.0173x over previous
//
#include <hip/hip_runtime.h>
#include <hip/hip_bf16.h>

// Problem constants
#define S_LEN   1024
#define BATCH   4
#define DMODEL  2048
#define NHEADS  16
#define NKVH    8
#define HEADD   128
#define NTOK    4096      // BATCH*S_LEN
#define QKV_CH  4096      // 2048 q + 1024 k + 1024 v

typedef __bf16 bf16x8 __attribute__((ext_vector_type(8)));
typedef float  f32x4  __attribute__((ext_vector_type(4)));

__device__ __forceinline__ float bf2f(unsigned short u) {
    return __uint_as_float(((unsigned)u) << 16);
}
__device__ __forceinline__ ushort f2bu(float f) {
    union { __hip_bfloat16 h; ushort u; } c;
    c.h = __float2bfloat16(f);
    return c.u;
}
// async global->LDS, 16B per lane; LDS dest must be wave-contiguous in lane order
__device__ __forceinline__ void gl_lds16(const ushort* g, ushort* l) {
    __builtin_amdgcn_global_load_lds(
        (const __attribute__((address_space(1))) void*)g,
        (__attribute__((address_space(3))) void*)l,
        16, 0, 0);
}

// ---------------- fp32 -> bf16 cast, 4 elems/thread ----------------
__global__ __launch_bounds__(256) void cast_kernel(const float* __restrict__ in,
                                                   __hip_bfloat16* __restrict__ out, int n4) {
    int i = blockIdx.x * 256 + threadIdx.x;
    if (i >= n4) return;
    float4 v = ((const float4*)in)[i];
    union { ushort4 u; __hip_bfloat16 h[4]; } r;
    r.h[0] = __float2bfloat16(v.x);
    r.h[1] = __float2bfloat16(v.y);
    r.h[2] = __float2bfloat16(v.z);
    r.h[3] = __float2bfloat16(v.w);
    ((ushort4*)out)[i] = r.u;
}

// ---------------- lB (e,d,r) fp32 -> Bt[d][e*16+r] bf16 ----------------
__global__ __launch_bounds__(256) void btrans_kernel(const float* __restrict__ lB,
                                                     ushort* __restrict__ Bt) {
    int idx = blockIdx.x * 256 + threadIdx.x;   // 131072
    int d = idx >> 6, er = idx & 63;
    int e = er >> 4, r = er & 15;
    Bt[idx] = f2bu(lB[((size_t)e * DMODEL + d) * 16 + r]);
}

// ---------------- gate: logits -> softmax -> top2 -> dense expert weights ----------------
__global__ __launch_bounds__(256) void gate_kernel(const float* __restrict__ X,
                                                   const float* __restrict__ GW,
                                                   float* __restrict__ EW) {
    __shared__ float red[4][257];
    const int t = blockIdx.x, tid = threadIdx.x;
    const float* x = X + (size_t)t * DMODEL;
    float p0 = 0.f, p1 = 0.f, p2 = 0.f, p3 = 0.f;
    for (int d = tid; d < DMODEL; d += 256) {
        float xv = x[d];
        p0 += xv * GW[d];
        p1 += xv * GW[DMODEL + d];
        p2 += xv * GW[2 * DMODEL + d];
        p3 += xv * GW[3 * DMODEL + d];
    }
    red[0][tid] = p0; red[1][tid] = p1; red[2][tid] = p2; red[3][tid] = p3;
    __syncthreads();
    for (int s = 128; s > 0; s >>= 1) {
        if (tid < s) {
            red[0][tid] += red[0][tid + s];
            red[1][tid] += red[1][tid + s];
            red[2][tid] += red[2][tid + s];
            red[3][tid] += red[3][tid + s];
        }
        __syncthreads();
    }
    if (tid == 0) {
        float l[4] = { red[0][0], red[1][0], red[2][0], red[3][0] };
        float mx = fmaxf(fmaxf(l[0], l[1]), fmaxf(l[2], l[3]));
        float pe[4], sum = 0.f;
        for (int e = 0; e < 4; e++) { pe[e] = __expf(l[e] - mx); sum += pe[e]; }
        float inv = 1.0f / sum;
        for (int e = 0; e < 4; e++) pe[e] *= inv;
        int i1 = 0;
        for (int e = 1; e < 4; e++) if (pe[e] > pe[i1]) i1 = e;
        int i2 = -1;
        for (int e = 0; e < 4; e++) if (e != i1 && (i2 < 0 || pe[e] > pe[i2])) i2 = e;
        float o[4] = {0.f, 0.f, 0.f, 0.f};
        o[i1] = pe[i1]; o[i2] = pe[i2];
        float* ew = EW + (size_t)t * 4;
        ew[0] = o[0]; ew[1] = o[1]; ew[2] = o[2]; ew[3] = o[3];
    }
}

// ---------------- bf16 MFMA GEMM, bf16 C: C[M][N] = bf16(A[M][K] * B[N][K]^T) ----------------
// 128x128 tile, 4 waves, global_load_lds staging (m97 structure).
__global__ __launch_bounds__(256) void gemm_bt_bf16(const ushort* __restrict__ A,
                                                    const ushort* __restrict__ B,
                                                    ushort* __restrict__ C,
                                                    int M, int N, int K) {
    __shared__ ushort As[128 * 32];
    __shared__ ushort Bs[128 * 32];
    const int tid  = threadIdx.x;
    const int wave = tid >> 6, lane = tid & 63;
    const int l16  = lane & 15, quad = lane >> 4;
    const int m0 = blockIdx.y * 128, n0 = blockIdx.x * 128;
    const int wm = (wave >> 1) * 64, wn = (wave & 1) * 64;

    f32x4 acc[4][4];
#pragma unroll
    for (int i = 0; i < 4; i++)
#pragma unroll
        for (int j = 0; j < 4; j++) acc[i][j] = (f32x4){0.f, 0.f, 0.f, 0.f};

    const int r1 = tid >> 2, kg1 = (tid & 3) * 8;
    const int r2 = (tid + 256) >> 2, kg2 = ((tid + 256) & 3) * 8;

    for (int k0 = 0; k0 < K; k0 += 32) {
        __syncthreads();
        gl_lds16(A + (size_t)(m0 + r1) * K + k0 + kg1, As + tid * 8);
        gl_lds16(B + (size_t)(n0 + r1) * K + k0 + kg1, Bs + tid * 8);
        gl_lds16(A + (size_t)(m0 + r2) * K + k0 + kg2, As + (tid + 256) * 8);
        gl_lds16(B + (size_t)(n0 + r2) * K + k0 + kg2, Bs + (tid + 256) * 8);
        __syncthreads();
        bf16x8 af[4], bfr[4];
#pragma unroll
        for (int i = 0; i < 4; i++) {
            af[i]  = *(const bf16x8*)(As + (wm + i * 16 + l16) * 32 + quad * 8);
            bfr[i] = *(const bf16x8*)(Bs + (wn + i * 16 + l16) * 32 + quad * 8);
        }
#pragma unroll
        for (int i = 0; i < 4; i++)
#pragma unroll
            for (int j = 0; j < 4; j++)
                acc[i][j] = __builtin_amdgcn_mfma_f32_16x16x32_bf16(af[i], bfr[j], acc[i][j], 0, 0, 0);
    }
#pragma unroll
    for (int i = 0; i < 4; i++)
#pragma unroll
        for (int j = 0; j < 4; j++)
#pragma unroll
            for (int r = 0; r < 4; r++) {
                int m = m0 + wm + i * 16 + quad * 4 + r;
                int n = n0 + wn + j * 16 + l16;
                C[(size_t)m * N + n] = f2bu(acc[i][j][r]);
            }
}

// ---------------- Wo GEMM with fused LoRA delta: C = A*B^T + A2*B2^T (fp32 out) ----------------
__global__ __launch_bounds__(256) void gemm_bt_lora(const ushort* __restrict__ A,
                                                    const ushort* __restrict__ B,
                                                    const ushort* __restrict__ A2,
                                                    const ushort* __restrict__ B2,
                                                    float* __restrict__ C) {
    __shared__ ushort As[128 * 32];
    __shared__ ushort Bs[128 * 32];
    const int tid  = threadIdx.x;
    const int wave = tid >> 6, lane = tid & 63;
    const int l16  = lane & 15, quad = lane >> 4;
    const int m0 = blockIdx.y * 128, n0 = blockIdx.x * 128;
    const int wm = (wave >> 1) * 64, wn = (wave & 1) * 64;
    const int K = DMODEL, N = DMODEL;

    f32x4 acc[4][4];
#pragma unroll
    for (int i = 0; i < 4; i++)
#pragma unroll
        for (int j = 0; j < 4; j++) acc[i][j] = (f32x4){0.f, 0.f, 0.f, 0.f};

    const int r1 = tid >> 2, kg1 = (tid & 3) * 8;
    const int r2 = (tid + 256) >> 2, kg2 = ((tid + 256) & 3) * 8;

    for (int k0 = 0; k0 < K; k0 += 32) {
        __syncthreads();
        gl_lds16(A + (size_t)(m0 + r1) * K + k0 + kg1, As + tid * 8);
        gl_lds16(B + (size_t)(n0 + r1) * K + k0 + kg1, Bs + tid * 8);
        gl_lds16(A + (size_t)(m0 + r2) * K + k0 + kg2, As + (tid + 256) * 8);
        gl_lds16(B + (size_t)(n0 + r2) * K + k0 + kg2, Bs + (tid + 256) * 8);
        __syncthreads();
        bf16x8 af[4], bfr[4];
#pragma unroll
        for (int i = 0; i < 4; i++) {
            af[i]  = *(const bf16x8*)(As + (wm + i * 16 + l16) * 32 + quad * 8);
            bfr[i] = *(const bf16x8*)(Bs + (wn + i * 16 + l16) * 32 + quad * 8);
        }
#pragma unroll
        for (int i = 0; i < 4; i++)
#pragma unroll
            for (int j = 0; j < 4; j++)
                acc[i][j] = __builtin_amdgcn_mfma_f32_16x16x32_bf16(af[i], bfr[j], acc[i][j], 0, 0, 0);
    }

    // LoRA delta: 2 extra K-steps over K2=64 (A2 stride 64, B2 stride 64)
#pragma unroll
    for (int k0 = 0; k0 < 64; k0 += 32) {
        __syncthreads();
        gl_lds16(A2 + (size_t)(m0 + r1) * 64 + k0 + kg1, As + tid * 8);
        gl_lds16(B2 + (size_t)(n0 + r1) * 64 + k0 + kg1, Bs + tid * 8);
        gl_lds16(A2 + (size_t)(m0 + r2) * 64 + k0 + kg2, As + (tid + 256) * 8);
        gl_lds16(B2 + (size_t)(n0 + r2) * 64 + k0 + kg2, Bs + (tid + 256) * 8);
        __syncthreads();
        bf16x8 af[4], bfr[4];
#pragma unroll
        for (int i = 0; i < 4; i++) {
            af[i]  = *(const bf16x8*)(As + (wm + i * 16 + l16) * 32 + quad * 8);
            bfr[i] = *(const bf16x8*)(Bs + (wn + i * 16 + l16) * 32 + quad * 8);
        }
#pragma unroll
        for (int i = 0; i < 4; i++)
#pragma unroll
            for (int j = 0; j < 4; j++)
                acc[i][j] = __builtin_amdgcn_mfma_f32_16x16x32_bf16(af[i], bfr[j], acc[i][j], 0, 0, 0);
    }

#pragma unroll
    for (int i = 0; i < 4; i++)
#pragma unroll
        for (int j = 0; j < 4; j++)
#pragma unroll
            for (int r = 0; r < 4; r++) {
                int m = m0 + wm + i * 16 + quad * 4 + r;
                int n = n0 + wn + j * 16 + l16;
                C[(size_t)m * N + n] = acc[i][j][r];
            }
}

// ---------------- LoRA H: G[t][e*16+r] = bf16(2*ew[t][e] * (x_t . A[e][r])) ----------------
__global__ __launch_bounds__(256) void lora_h_kernel(const ushort* __restrict__ X,
                                                     const ushort* __restrict__ Acat,
                                                     const float* __restrict__ EW,
                                                     ushort* __restrict__ G) {
    __shared__ ushort As[64 * 32];
    __shared__ ushort Bs[64 * 32];
    const int tid = threadIdx.x;
    const int wave = tid >> 6, lane = tid & 63;
    const int l16 = lane & 15, quad = lane >> 4;
    const int m0 = blockIdx.x * 64;

    f32x4 acc[4];
#pragma unroll
    for (int nt = 0; nt < 4; nt++) acc[nt] = (f32x4){0.f, 0.f, 0.f, 0.f};

    const int r1 = tid >> 2, kg1 = (tid & 3) * 8;

    for (int k0 = 0; k0 < DMODEL; k0 += 32) {
        __syncthreads();
        gl_lds16(X + (size_t)(m0 + r1) * DMODEL + k0 + kg1, As + tid * 8);
        gl_lds16(Acat + (size_t)r1 * DMODEL + k0 + kg1, Bs + tid * 8);
        __syncthreads();
        bf16x8 af = *(const bf16x8*)(As + (wave * 16 + l16) * 32 + quad * 8);
#pragma unroll
        for (int nt = 0; nt < 4; nt++) {
            bf16x8 bfr = *(const bf16x8*)(Bs + (nt * 16 + l16) * 32 + quad * 8);
            acc[nt] = __builtin_amdgcn_mfma_f32_16x16x32_bf16(af, bfr, acc[nt], 0, 0, 0);
        }
    }
#pragma unroll
    for (int nt = 0; nt < 4; nt++)
#pragma unroll
        for (int r = 0; r < 4; r++) {
            int m = m0 + wave * 16 + quad * 4 + r;
            float wsc = 2.0f * EW[(size_t)m * 4 + nt];   // LORA_SCALE=2 folded
            G[(size_t)m * 64 + nt * 16 + l16] = f2bu(acc[nt][r] * wsc);
        }
}

// ---------------- RMSNorm + RoPE: bf16 qkv -> bf16 Qb[b,h,s,d] (scaled), Kb[b,kv,s,d] ----------------
__global__ __launch_bounds__(256) void normrope_kernel(const ushort* __restrict__ QKV,
                                                       const float* __restrict__ cosb,
                                                       const float* __restrict__ sinb,
                                                       const float* __restrict__ qw,
                                                       const float* __restrict__ kw,
                                                       ushort* __restrict__ Qb,
                                                       ushort* __restrict__ Kb) {
    const int wave = threadIdx.x >> 6, lane = threadIdx.x & 63;
    const int r = blockIdx.x * 4 + wave;
    const ushort* p; const float* w; int t; ushort* dst; float scale;
    if (r < NTOK * NHEADS) {
        t = r >> 4;
        int h = r & 15;
        p = QKV + (size_t)t * QKV_CH + h * HEADD;
        w = qw; scale = 0.08838834764831845f;   // 128^-0.5 folded into Q
        int b = t >> 10, s = t & 1023;
        dst = Qb + ((size_t)((b * 16 + h) * 1024 + s)) * HEADD;
    } else {
        int r2 = r - NTOK * NHEADS;
        t = r2 >> 3;
        int kv = r2 & 7;
        p = QKV + (size_t)t * QKV_CH + 2048 + kv * HEADD;
        w = kw; scale = 1.0f;
        int b = t >> 10, s = t & 1023;
        dst = Kb + ((size_t)((b * 8 + kv) * 1024 + s)) * HEADD;
    }
    float xl = bf2f(p[lane]), xh = bf2f(p[lane + 64]);
    float ss = xl * xl + xh * xh;
#pragma unroll
    for (int mask = 1; mask < 64; mask <<= 1) ss += __shfl_xor(ss, mask);
    float rstd = rsqrtf(ss * (1.0f / 128.0f) + 1e-6f);
    float nl = xl * rstd * w[lane];
    float nh = xh * rstd * w[lane + 64];
    const float* cp = cosb + (size_t)t * HEADD;
    const float* sp = sinb + (size_t)t * HEADD;
    float ol = nl * cp[lane]      - nh * sp[lane];
    float oh = nh * cp[lane + 64] + nl * sp[lane + 64];
    dst[lane]      = f2bu(ol * scale);
    dst[lane + 64] = f2bu(oh * scale);
}

// ---------------- V transpose: bf16 qkv v -> bf16 Vt[b,kv,d,s] ----------------
#define TPITCH 136
__global__ __launch_bounds__(256) void vtrans_kernel(const ushort* __restrict__ QKV,
                                                     ushort* __restrict__ Vt) {
    __shared__ __align__(16) ushort Ts[64 * TPITCH];
    const int blk = blockIdx.x;          // 4*8*16
    const int sc = blk & 15;
    const int kvb = blk >> 4;            // b*8+kv
    const int s0 = sc * 64;
    const ushort* src = QKV + ((size_t)((kvb >> 3) * 1024 + s0)) * QKV_CH + 3072 + (kvb & 7) * HEADD;
    for (int c = threadIdx.x; c < 1024; c += 256) {
        int s = c >> 4, d0 = (c & 15) * 8;
        *(uint4*)(Ts + s * TPITCH + d0) = *(const uint4*)(src + (size_t)s * QKV_CH + d0);
    }
    __syncthreads();
    ushort* dst = Vt + ((size_t)kvb * HEADD) * S_LEN + s0;
    for (int c = threadIdx.x; c < 1024; c += 256) {
        int d = c >> 3, s8 = (c & 7) * 8;
        union { ushort u[8]; uint4 v; } pk;
#pragma unroll
        for (int j = 0; j < 8; j++) pk.u[j] = Ts[(s8 + j) * TPITCH + d];
        *(uint4*)(dst + (size_t)d * S_LEN + s8) = pk.v;
    }
}

// ---------------- flash attention (bf16 MFMA, no-max softmax — exact by boundedness) ----------------
// |q|=|k|=sqrt(128) after rmsnorm, scale 1/sqrt(128) => |s|<=11.4, exp(s)<=9e4: fp32/bf16 safe.
#define KPITCH 136
#define VPITCH 72
__global__ __launch_bounds__(256) void fattn_kernel(const ushort* __restrict__ Qb,
                                                    const ushort* __restrict__ Kb,
                                                    const ushort* __restrict__ Vt,
                                                    __hip_bfloat16* __restrict__ O) {
    __shared__ __align__(16) ushort Ks[64 * KPITCH];
    __shared__ __align__(16) ushort Vs[128 * VPITCH];
    __shared__ __align__(16) ushort Ps[4 * 16 * VPITCH];
    const int tid = threadIdx.x;
    const int wq = tid >> 6, lane = tid & 63;
    const int l16 = lane & 15, quad = lane >> 4;
    const int qblk = 15 - (blockIdx.x >> 6);    // heavy q-blocks first
    const int bh = blockIdx.x & 63;
    const int b = bh >> 4, h = bh & 15;
    const int kvb = b * 8 + (h >> 1);
    const int q0 = qblk * 64;
    const int qbase = q0 + wq * 16;

    bf16x8 qf[4];
    const ushort* qrow = Qb + ((size_t)bh * S_LEN + qbase + l16) * HEADD;
#pragma unroll
    for (int kt = 0; kt < 4; kt++)
        qf[kt] = *(const bf16x8*)(qrow + kt * 32 + quad * 8);

    f32x4 oacc[8];
#pragma unroll
    for (int dt = 0; dt < 8; dt++) oacc[dt] = (f32x4){0.f, 0.f, 0.f, 0.f};
    float l[4] = { 0.f, 0.f, 0.f, 0.f };   // per-lane partial denominators

    const ushort* kbase = Kb + (size_t)kvb * S_LEN * HEADD;
    const ushort* vbase = Vt + (size_t)kvb * HEADD * S_LEN;
    const int ntiles = qblk + 1;

    for (int kb = 0; kb < ntiles; kb++) {
        const int k0 = kb * 64;
        __syncthreads();
        for (int c = tid; c < 1024; c += 256) {
            int row = c >> 4, col = (c & 15) * 8;
            *(uint4*)(Ks + row * KPITCH + col) =
                *(const uint4*)(kbase + (size_t)(k0 + row) * HEADD + col);
        }
        for (int c = tid; c < 1024; c += 256) {
            int row = c >> 3, col = (c & 7) * 8;
            *(uint4*)(Vs + row * VPITCH + col) =
                *(const uint4*)(vbase + (size_t)row * S_LEN + k0 + col);
        }
        __syncthreads();

        f32x4 sacc[4];
#pragma unroll
        for (int nt = 0; nt < 4; nt++) sacc[nt] = (f32x4){0.f, 0.f, 0.f, 0.f};
#pragma unroll
        for (int kt = 0; kt < 4; kt++) {
#pragma unroll
            for (int nt = 0; nt < 4; nt++) {
                bf16x8 kf = *(const bf16x8*)(Ks + (nt * 16 + l16) * KPITCH + kt * 32 + quad * 8);
                sacc[nt] = __builtin_amdgcn_mfma_f32_16x16x32_bf16(qf[kt], kf, sacc[nt], 0, 0, 0);
            }
        }

        // p = exp(s) (no max subtraction), causal mask, accumulate partial l
#pragma unroll
        for (int r = 0; r < 4; r++) {
            const int qg = qbase + quad * 4 + r;
#pragma unroll
            for (int nt = 0; nt < 4; nt++) {
                int kg = k0 + nt * 16 + l16;
                float p = (kg <= qg) ? __expf(sacc[nt][r]) : 0.f;
                l[r] += p;
                Ps[wq * 16 * VPITCH + (quad * 4 + r) * VPITCH + nt * 16 + l16] = f2bu(p);
            }
        }

        // O += P V (unnormalized, no rescale needed)
#pragma unroll
        for (int kt2 = 0; kt2 < 2; kt2++) {
            bf16x8 pf = *(const bf16x8*)(Ps + wq * 16 * VPITCH + l16 * VPITCH + kt2 * 32 + quad * 8);
#pragma unroll
            for (int dt = 0; dt < 8; dt++) {
                bf16x8 vf = *(const bf16x8*)(Vs + (dt * 16 + l16) * VPITCH + kt2 * 32 + quad * 8);
                oacc[dt] = __builtin_amdgcn_mfma_f32_16x16x32_bf16(pf, vf, oacc[dt], 0, 0, 0);
            }
        }
    }

    // epilogue: reduce l across the 16-lane key groups, normalize, store
#pragma unroll
    for (int r = 0; r < 4; r++) {
        float lr = l[r];
        lr += __shfl_xor(lr, 1);
        lr += __shfl_xor(lr, 2);
        lr += __shfl_xor(lr, 4);
        lr += __shfl_xor(lr, 8);
        float inv = 1.0f / lr;
        size_t base = ((size_t)(b * S_LEN + qbase + quad * 4 + r)) * (NHEADS * HEADD) + h * HEADD;
#pragma unroll
        for (int dt = 0; dt < 8; dt++)
            O[base + dt * 16 + l16] = __float2bfloat16(oacc[dt][r] * inv);
    }
}

extern "C" void kernel_launch(void* const* d_in, const int* in_sizes, int n_in,
                              void* d_out, int out_size, void* d_ws, size_t ws_size,
                              hipStream_t stream) {
    const float* hidden = (const float*)d_in[0];
    const float* cosb   = (const float*)d_in[1];
    const float* sinb   = (const float*)d_in[2];
    const float* Wq     = (const float*)d_in[3];
    const float* Wk     = (const float*)d_in[4];
    const float* Wv     = (const float*)d_in[5];
    const float* Wo     = (const float*)d_in[6];
    const float* qnw    = (const float*)d_in[7];
    const float* knw    = (const float*)d_in[8];
    const float* gw     = (const float*)d_in[9];
    const float* lA     = (const float*)d_in[10];
    const float* lB     = (const float*)d_in[11];
    float* out = (float*)d_out;

    // workspace layout (max ~72 MB, lifetime-aliased):
    //  [0,16M):    hid_bf (dead after QKV gemm)   -> Qb (normrope)
    //  [16M,32M):  wqkv_bf (dead after QKV gemm)  -> Kb [16,24) + Vt [24,32)
    //  [32M,40M):  wo_bf (live to final gemm)
    //  [40M,72M):  qkv_bf C (dead after normrope+vtrans) -> attn_bf [40,56) + Acat/Bt/G @56M
    //  [72M,+64K): ew (written by gate, read by lora_h)
    char* ws = (char*)d_ws;
    __hip_bfloat16* hid_bf  = (__hip_bfloat16*)ws;
    __hip_bfloat16* wqkv_bf = (__hip_bfloat16*)(ws + (16u << 20));
    __hip_bfloat16* wo_bf   = (__hip_bfloat16*)(ws + (32u << 20));
    ushort*         qkv_bf  = (ushort*)(ws + (40u << 20));
    float*          ew      = (float*)(ws + (72u << 20));
    ushort*         Qb      = (ushort*)ws;                          // alias hid_bf
    ushort*         Kb      = (ushort*)(ws + (16u << 20));          // alias wqkv_bf[0:8M)
    ushort*         Vt      = (ushort*)(ws + (24u << 20));          // alias wqkv_bf[8M:16M)
    __hip_bfloat16* attn_bf = (__hip_bfloat16*)(ws + (40u << 20));  // alias qkv_bf[0:16M)
    ushort*         Acat    = (ushort*)(ws + (56u << 20));                 // 256 KB
    ushort*         Bt      = (ushort*)(ws + (56u << 20) + (256u << 10));  // 256 KB
    ushort*         G       = (ushort*)(ws + (56u << 20) + (512u << 10));  // 512 KB

    // 1. casts
    cast_kernel<<<8192, 256, 0, stream>>>(hidden, hid_bf, 2097152);
    cast_kernel<<<4096, 256, 0, stream>>>(Wq, wqkv_bf,            1048576);
    cast_kernel<<<2048, 256, 0, stream>>>(Wk, wqkv_bf + 4194304,  524288);
    cast_kernel<<<2048, 256, 0, stream>>>(Wv, wqkv_bf + 6291456,  524288);
    cast_kernel<<<4096, 256, 0, stream>>>(Wo, wo_bf,              1048576);

    // 2. gate
    gate_kernel<<<4096, 256, 0, stream>>>(hidden, gw, ew);

    // 3. fused QKV projection (M=4096, N=4096, K=2048) -> bf16 qkv
    gemm_bt_bf16<<<dim3(32, 32), 256, 0, stream>>>((const ushort*)hid_bf, (const ushort*)wqkv_bf,
                                                   qkv_bf, NTOK, QKV_CH, DMODEL);

    // 4. RMSNorm + RoPE -> Qb/Kb ; V transpose -> Vt (qkv_bf dead after these)
    normrope_kernel<<<24576, 256, 0, stream>>>(qkv_bf, cosb, sinb, qnw, knw, Qb, Kb);
    vtrans_kernel<<<512, 256, 0, stream>>>(qkv_bf, Vt);

    // 5. LoRA weight prep (into dead qkv_bf region — must follow normrope+vtrans)
    cast_kernel<<<128, 256, 0, stream>>>(lA, (__hip_bfloat16*)Acat, 32768);
    btrans_kernel<<<512, 256, 0, stream>>>(lB, Bt);

    // 6. flash attention -> attn_bf
    fattn_kernel<<<1024, 256, 0, stream>>>(Qb, Kb, Vt, attn_bf);

    // 7. LoRA H: G = 2*ew*(attn @ Acat^T)  (M=4096, N=64, K=2048)
    lora_h_kernel<<<64, 256, 0, stream>>>((const ushort*)attn_bf, Acat, ew, G);

    // 8. output projection + fused LoRA delta -> d_out
    gemm_bt_lora<<<dim3(16, 32), 256, 0, stream>>>((const ushort*)attn_bf, (const ushort*)wo_bf,
                                                   G, Bt, out);
}